// Round 10
// baseline (947.988 us; speedup 1.0000x reference)
//
#include <hip/hip_runtime.h>
#include <hip/hip_bf16.h>
#include <stdint.h>

typedef __attribute__((ext_vector_type(8))) short short8;        // 8 bf16 (MFMA frag)
typedef __attribute__((ext_vector_type(4))) float f32x4;
typedef __attribute__((ext_vector_type(16))) float f32x16;       // 32x32 acc
typedef __attribute__((ext_vector_type(8))) unsigned short u16x8;

static __device__ __forceinline__ unsigned short f2bf(float f) {
  union { float f; unsigned int u; } c; c.f = f;
  unsigned int u = c.u;
  u += 0x7FFFu + ((u >> 16) & 1u);
  return (unsigned short)(u >> 16);
}
static __device__ __forceinline__ f32x16 mfma32(short8 a, short8 b, f32x16 c) {
  return __builtin_amdgcn_mfma_f32_32x32x16_bf16(a, b, c, 0, 0, 0);
}
static __device__ __forceinline__ void gl_lds16(const void* g, void* lds) {
  __builtin_amdgcn_global_load_lds(
      (const __attribute__((address_space(1))) void*)(unsigned long long)(uintptr_t)g,
      (__attribute__((address_space(3))) void*)(unsigned int)(uintptr_t)lds,
      16, 0, 0);
}

// ---------------------------------------------------------------------------
// convert kernels (unchanged, BW-bound)
// ---------------------------------------------------------------------------
__global__ void k_cvt_w(const float* __restrict__ w, const float* __restrict__ s,
                        unsigned short* __restrict__ o, int N, int K) {
  const int KB = K >> 7;
  const size_t total = ((size_t)N * K) >> 3;
  for (size_t i = (size_t)blockIdx.x * blockDim.x + threadIdx.x; i < total;
       i += (size_t)gridDim.x * blockDim.x) {
    const size_t e = i << 3;
    const int n = (int)(e / K);
    const int k = (int)(e % K);
    const float sc = s[(n >> 7) * KB + (k >> 7)];
    f32x4 a = *(const f32x4*)(w + e);
    f32x4 b = *(const f32x4*)(w + e + 4);
    u16x8 q;
    #pragma unroll
    for (int j = 0; j < 4; ++j) { q[j] = f2bf(a[j] * sc); q[4 + j] = f2bf(b[j] * sc); }
    *(u16x8*)(o + e) = q;
  }
}

__global__ void k_cvt_x(const float* __restrict__ x, unsigned short* __restrict__ o,
                        size_t total8) {
  for (size_t i = (size_t)blockIdx.x * blockDim.x + threadIdx.x; i < total8;
       i += (size_t)gridDim.x * blockDim.x) {
    const size_t e = i << 3;
    f32x4 a = *(const f32x4*)(x + e);
    f32x4 b = *(const f32x4*)(x + e + 4);
    u16x8 q;
    #pragma unroll
    for (int j = 0; j < 4; ++j) { q[j] = f2bf(a[j]); q[4 + j] = f2bf(b[j]); }
    *(u16x8*)(o + e) = q;
  }
}

// ---------------------------------------------------------------------------
// Fused gate+up GEMM + SwiGLU — R9 loop structure (proven), MFMA 32x32x16.
//   h = silu(xb @ w1b^T) * (xb @ w3b^T)  -> bf16 [M][N]
// BM=256, BN=128, BK=64; 512 thr = 8 waves (2Mx4N); per-wave 128x32 x2 mats
// as 4 frags of 32x32 each. A-frag & B-frag read: lane l -> LDS row (l&31),
// k-slot byte off = ks*32 + (l>>5)*16 (symmetric A/B). XOR swizzle value
// unchanged: (lane&7)<<4. C/D: col=lane&31, row=(reg&3)+8*(reg>>2)+4*(l>>5)
// [m74/m101-verified]. vmcnt(8)/lgkm(0)/barrier protocol identical to R9.
// ---------------------------------------------------------------------------
__global__ __launch_bounds__(512, 2)
void k_gateup_f(const unsigned short* __restrict__ A,
                const unsigned short* __restrict__ B1,
                const unsigned short* __restrict__ B3,
                unsigned short* __restrict__ H,
                int N, int K) {
  __shared__ unsigned short lds[65536];   // 128KB

  const int tid  = threadIdx.x;
  const int lane = tid & 63;
  const int wid  = tid >> 6;
  const int wm   = wid >> 2;              // 0..1
  const int wn   = wid & 3;               // 0..3
  const int lr31 = lane & 31;
  const int hi   = lane >> 5;             // 0..1
  const int xr   = (lane & 7) << 4;

  const int nwg = gridDim.x;              // 896, %8==0
  const int per = nwg >> 3;
  const int wg  = (int)blockIdx.x;
  const int swz = (wg & 7) * per + (wg >> 3);
  const int bm  = swz & 7;
  const int bn  = swz >> 3;

  const int r0   = tid >> 3;
  const int colb = ((tid & 7) ^ ((tid >> 3) & 7)) << 4;
  const size_t ldb = (size_t)K * 2;

  const char* gA = (const char*)A  + (size_t)bm * 256 * ldb;
  const char* g1 = (const char*)B1 + (size_t)bn * 128 * ldb;
  const char* g3 = (const char*)B3 + (size_t)bn * 128 * ldb;

  auto stage = [&](int t) {
    const size_t kb = (size_t)t * 128;
    #pragma unroll
    for (int h = 0; h < 2; ++h) {          // A: 4 loads
      unsigned short* d = lds + (((2 * t + h) & 3) * 8192) + wid * 512;
      const char* s = gA + (size_t)(h * 128 + r0) * ldb + kb + colb;
      gl_lds16(s,            d);
      gl_lds16(s + 64 * ldb, d + 4096);
    }
    {                                      // B1: 2 loads
      unsigned short* d = lds + 32768 + ((t & 1) * 8192) + wid * 512;
      const char* s = g1 + (size_t)r0 * ldb + kb + colb;
      gl_lds16(s,            d);
      gl_lds16(s + 64 * ldb, d + 4096);
    }
    {                                      // B3: 2 loads
      unsigned short* d = lds + 49152 + ((t & 1) * 8192) + wid * 512;
      const char* s = g3 + (size_t)r0 * ldb + kb + colb;
      gl_lds16(s,            d);
      gl_lds16(s + 64 * ldb, d + 4096);
    }
  };

  f32x16 accg[4], accu[4];
  #pragma unroll
  for (int f = 0; f < 4; ++f)
    #pragma unroll
    for (int e = 0; e < 16; ++e) { accg[f][e] = 0.0f; accu[f][e] = 0.0f; }

  const int wrow0 = wn * 32;              // wave's B-row (=output col) base
  const int NT = K >> 6;

  // per-frag read offsets (byte): row*128 + ks*32 + hi*16, XOR xr
  const int aRow = lr31;                  // + f*32
  const int bRow = wrow0 + lr31;

  stage(0);
  stage(1);

  for (int t = 0; t < NT; ++t) {
    if (t == NT - 1) asm volatile("s_waitcnt vmcnt(0)" ::: "memory");
    else             asm volatile("s_waitcnt vmcnt(8)" ::: "memory");
    __builtin_amdgcn_s_barrier();
    __builtin_amdgcn_sched_barrier(0);

    const char* ab  = (const char*)lds + (((2 * t + wm) & 3) * 16384);
    const char* b1b = (const char*)lds + 65536 + ((t & 1) * 16384);
    const char* b3b = (const char*)lds + 98304 + ((t & 1) * 16384);

    short8 a0[4][2], p0[2], q0[2], a1[4][2], p1[2], q1[2];
    // cluster 0: k-slots 0,1
    #pragma unroll
    for (int f = 0; f < 4; ++f) {
      a0[f][0] = *(const short8*)(ab + ((((f * 32 + aRow) * 128) + 0 * 32 + hi * 16) ^ xr));
      a0[f][1] = *(const short8*)(ab + ((((f * 32 + aRow) * 128) + 1 * 32 + hi * 16) ^ xr));
    }
    #pragma unroll
    for (int s = 0; s < 2; ++s) {
      p0[s] = *(const short8*)(b1b + (((bRow * 128) + s * 32 + hi * 16) ^ xr));
      q0[s] = *(const short8*)(b3b + (((bRow * 128) + s * 32 + hi * 16) ^ xr));
    }
    #pragma unroll
    for (int f = 0; f < 4; ++f)
      #pragma unroll
      for (int s = 0; s < 2; ++s) {
        accg[f] = mfma32(a0[f][s], p0[s], accg[f]);
        accu[f] = mfma32(a0[f][s], q0[s], accu[f]);
      }

    // cluster 1: k-slots 2,3 (reads issued, then drain+barrier+stage)
    #pragma unroll
    for (int f = 0; f < 4; ++f) {
      a1[f][0] = *(const short8*)(ab + ((((f * 32 + aRow) * 128) + 2 * 32 + hi * 16) ^ xr));
      a1[f][1] = *(const short8*)(ab + ((((f * 32 + aRow) * 128) + 3 * 32 + hi * 16) ^ xr));
    }
    #pragma unroll
    for (int s = 0; s < 2; ++s) {
      p1[s] = *(const short8*)(b1b + (((bRow * 128) + (2 + s) * 32 + hi * 16) ^ xr));
      q1[s] = *(const short8*)(b3b + (((bRow * 128) + (2 + s) * 32 + hi * 16) ^ xr));
    }

    asm volatile("s_waitcnt lgkmcnt(0)" ::: "memory");
    __builtin_amdgcn_s_barrier();
    __builtin_amdgcn_sched_barrier(0);
    if (t + 2 < NT) stage(t + 2);
    __builtin_amdgcn_sched_barrier(0);

    #pragma unroll
    for (int f = 0; f < 4; ++f)
      #pragma unroll
      for (int s = 0; s < 2; ++s) {
        accg[f] = mfma32(a1[f][s], p1[s], accg[f]);
        accu[f] = mfma32(a1[f][s], q1[s], accu[f]);
      }
  }

  // epilogue: silu(g)*u; 32x32 C/D map col=lane&31, row=(r&3)+8*(r>>2)+4*hi
  const int growb = bm * 256 + wm * 128;
  const int gcol  = bn * 128 + wn * 32 + lr31;
  #pragma unroll
  for (int f = 0; f < 4; ++f)
    #pragma unroll
    for (int r = 0; r < 16; ++r) {
      const int row = growb + f * 32 + (r & 3) + 8 * (r >> 2) + 4 * hi;
      const float g  = accg[f][r];
      const float u  = accu[f][r];
      const float sg = g / (1.0f + __expf(-g));
      H[(size_t)row * N + gcol] = f2bf(sg * u);
    }
}

// ---------------------------------------------------------------------------
// Down GEMM — R9 structure, MFMA 32x32x16: y = h @ w2b^T, f32 out.
// ---------------------------------------------------------------------------
__global__ __launch_bounds__(512, 2)
void k_down256(const unsigned short* __restrict__ A,
               const unsigned short* __restrict__ B,
               float* __restrict__ Y,
               int N, int K) {
  __shared__ unsigned short lds[65536];   // 128KB (A ring 64KB + B ring 64KB)

  const int tid  = threadIdx.x;
  const int lane = tid & 63;
  const int wid  = tid >> 6;
  const int wm   = wid >> 2;
  const int wn   = wid & 3;
  const int lr31 = lane & 31;
  const int hi   = lane >> 5;
  const int xr   = (lane & 7) << 4;

  const int nwg = gridDim.x;              // 256
  const int per = nwg >> 3;
  const int wg  = (int)blockIdx.x;
  const int swz = (wg & 7) * per + (wg >> 3);
  const int bm  = swz & 7;
  const int bn  = swz >> 3;

  const int r0   = tid >> 3;
  const int colb = ((tid & 7) ^ ((tid >> 3) & 7)) << 4;
  const size_t ldb = (size_t)K * 2;

  const char* gA = (const char*)A + (size_t)bm * 256 * ldb;
  const char* gB = (const char*)B + (size_t)bn * 128 * ldb;

  auto stage = [&](int t) {
    const size_t kb = (size_t)t * 128;
    #pragma unroll
    for (int h = 0; h < 2; ++h) {
      unsigned short* d = lds + (((2 * t + h) & 3) * 8192) + wid * 512;
      const char* s = gA + (size_t)(h * 128 + r0) * ldb + kb + colb;
      gl_lds16(s,            d);
      gl_lds16(s + 64 * ldb, d + 4096);
    }
    {
      unsigned short* d = lds + 32768 + ((t & 3) * 8192) + wid * 512;
      const char* s = gB + (size_t)r0 * ldb + kb + colb;
      gl_lds16(s,            d);
      gl_lds16(s + 64 * ldb, d + 4096);
    }
  };

  f32x16 acc[4];
  #pragma unroll
  for (int f = 0; f < 4; ++f)
    #pragma unroll
    for (int e = 0; e < 16; ++e) acc[f][e] = 0.0f;

  const int wrow0 = wn * 32;
  const int NT = K >> 6;
  const int aRow = lr31;
  const int bRow = wrow0 + lr31;

  stage(0);
  stage(1);

  for (int t = 0; t < NT; ++t) {
    if (t == NT - 1) asm volatile("s_waitcnt vmcnt(0)" ::: "memory");
    else             asm volatile("s_waitcnt vmcnt(6)" ::: "memory");
    __builtin_amdgcn_s_barrier();
    __builtin_amdgcn_sched_barrier(0);

    const char* ab = (const char*)lds + (((2 * t + wm) & 3) * 16384);
    const char* bb = (const char*)lds + 65536 + ((t & 3) * 16384);

    short8 a0[4][2], b0[2], a1[4][2], b1[2];
    #pragma unroll
    for (int f = 0; f < 4; ++f) {
      a0[f][0] = *(const short8*)(ab + ((((f * 32 + aRow) * 128) + 0 * 32 + hi * 16) ^ xr));
      a0[f][1] = *(const short8*)(ab + ((((f * 32 + aRow) * 128) + 1 * 32 + hi * 16) ^ xr));
    }
    #pragma unroll
    for (int s = 0; s < 2; ++s)
      b0[s] = *(const short8*)(bb + (((bRow * 128) + s * 32 + hi * 16) ^ xr));
    #pragma unroll
    for (int f = 0; f < 4; ++f)
      #pragma unroll
      for (int s = 0; s < 2; ++s)
        acc[f] = mfma32(a0[f][s], b0[s], acc[f]);

    #pragma unroll
    for (int f = 0; f < 4; ++f) {
      a1[f][0] = *(const short8*)(ab + ((((f * 32 + aRow) * 128) + 2 * 32 + hi * 16) ^ xr));
      a1[f][1] = *(const short8*)(ab + ((((f * 32 + aRow) * 128) + 3 * 32 + hi * 16) ^ xr));
    }
    #pragma unroll
    for (int s = 0; s < 2; ++s)
      b1[s] = *(const short8*)(bb + (((bRow * 128) + (2 + s) * 32 + hi * 16) ^ xr));

    asm volatile("s_waitcnt lgkmcnt(0)" ::: "memory");
    __builtin_amdgcn_s_barrier();
    __builtin_amdgcn_sched_barrier(0);
    if (t + 2 < NT) stage(t + 2);
    __builtin_amdgcn_sched_barrier(0);

    #pragma unroll
    for (int f = 0; f < 4; ++f)
      #pragma unroll
      for (int s = 0; s < 2; ++s)
        acc[f] = mfma32(a1[f][s], b1[s], acc[f]);
  }

  const int growb = bm * 256 + wm * 128;
  const int gcol  = bn * 128 + wn * 32 + lr31;
  #pragma unroll
  for (int f = 0; f < 4; ++f)
    #pragma unroll
    for (int r = 0; r < 16; ++r) {
      const int row = growb + f * 32 + (r & 3) + 8 * (r >> 2) + 4 * hi;
      Y[(size_t)row * N + gcol] = acc[f][r];
    }
}

extern "C" void kernel_launch(void* const* d_in, const int* in_sizes, int n_in,
                              void* d_out, int out_size, void* d_ws, size_t ws_size,
                              hipStream_t stream) {
  const float* x   = (const float*)d_in[0];
  const float* w1  = (const float*)d_in[1];
  const float* w1s = (const float*)d_in[2];
  const float* w3  = (const float*)d_in[3];
  const float* w3s = (const float*)d_in[4];
  const float* w2  = (const float*)d_in[5];
  const float* w2s = (const float*)d_in[6];
  float* y = (float*)d_out;

  const int D = 4096, I = 14336;
  const int T = in_sizes[0] / D;          // 2048

  const size_t xbB = (size_t)T * D * 2;
  const size_t wB  = (size_t)I * D * 2;

  char* ws = (char*)d_ws;
  unsigned short* xb  = (unsigned short*)(ws);
  unsigned short* w1b = (unsigned short*)(ws + xbB);
  unsigned short* w3b = (unsigned short*)(ws + xbB + wB);
  unsigned short* w2b = (unsigned short*)(ws + xbB + 2 * wB);
  unsigned short* h   = (unsigned short*)(ws + xbB + 3 * wB);

  k_cvt_x<<<2048, 256, 0, stream>>>(x, xb, ((size_t)T * D) >> 3);
  k_cvt_w<<<2048, 256, 0, stream>>>(w1, w1s, w1b, I, D);
  k_cvt_w<<<2048, 256, 0, stream>>>(w3, w3s, w3b, I, D);
  k_cvt_w<<<2048, 256, 0, stream>>>(w2, w2s, w2b, D, I);

  // fused gate+up+SwiGLU: h = silu(xb@w1b^T) * (xb@w3b^T)   grid 8*112 = 896
  k_gateup_f<<<dim3((T / 256) * (I / 128)), dim3(512), 0, stream>>>(
      xb, w1b, w3b, h, I, D);
  // down: y = h @ w2b^T                                     grid 8*32 = 256
  k_down256<<<dim3((T / 256) * (D / 128)), dim3(512), 0, stream>>>(
      h, w2b, y, D, I);
}

// Round 11
// 860.609 us; speedup vs baseline: 1.1015x; 1.1015x over previous
//
#include <hip/hip_runtime.h>
#include <hip/hip_bf16.h>
#include <stdint.h>

typedef __attribute__((ext_vector_type(8))) short short8;       // 8 bf16 (MFMA frag)
typedef __attribute__((ext_vector_type(4))) float f32x4;
typedef __attribute__((ext_vector_type(8))) unsigned short u16x8;

static __device__ __forceinline__ unsigned short f2bf(float f) {
  union { float f; unsigned int u; } c; c.f = f;
  unsigned int u = c.u;
  u += 0x7FFFu + ((u >> 16) & 1u);
  return (unsigned short)(u >> 16);
}
static __device__ __forceinline__ f32x4 mfma_bf16(short8 a, short8 b, f32x4 c) {
  return __builtin_amdgcn_mfma_f32_16x16x32_bf16(a, b, c, 0, 0, 0);
}
static __device__ __forceinline__ void gl_lds16(const void* g, void* lds) {
  __builtin_amdgcn_global_load_lds(
      (const __attribute__((address_space(1))) void*)(unsigned long long)(uintptr_t)g,
      (__attribute__((address_space(3))) void*)(unsigned int)(uintptr_t)lds,
      16, 0, 0);
}

// ---------------------------------------------------------------------------
// Merged convert pass: x -> bf16, and w1/w3/w2 dequant -> bf16, one launch.
// Flat 8-element-chunk index over x | w1 | w3 | w2 (divergence only at the
// 3 range boundaries). HBM-roofline-bound: ~1.18 GB total traffic.
// ---------------------------------------------------------------------------
__global__ void k_cvt_all(const float* __restrict__ x,
                          const float* __restrict__ w1, const float* __restrict__ w1s,
                          const float* __restrict__ w3, const float* __restrict__ w3s,
                          const float* __restrict__ w2, const float* __restrict__ w2s,
                          unsigned short* __restrict__ xb,
                          unsigned short* __restrict__ w1b,
                          unsigned short* __restrict__ w3b,
                          unsigned short* __restrict__ w2b,
                          size_t nx8, size_t nw8, size_t nd8) {
  const size_t total = nx8 + 2 * nw8 + nd8;
  for (size_t i = (size_t)blockIdx.x * blockDim.x + threadIdx.x; i < total;
       i += (size_t)gridDim.x * blockDim.x) {
    const float* src; unsigned short* dst; const float* sarr;
    size_t e; int K;
    if (i < nx8) {
      e = i << 3;
      f32x4 a = *(const f32x4*)(x + e);
      f32x4 b = *(const f32x4*)(x + e + 4);
      u16x8 q;
      #pragma unroll
      for (int j = 0; j < 4; ++j) { q[j] = f2bf(a[j]); q[4 + j] = f2bf(b[j]); }
      *(u16x8*)(xb + e) = q;
      continue;
    } else if (i < nx8 + nw8) {
      e = (i - nx8) << 3;  src = w1; dst = w1b; sarr = w1s; K = 4096;
    } else if (i < nx8 + 2 * nw8) {
      e = (i - nx8 - nw8) << 3;  src = w3; dst = w3b; sarr = w3s; K = 4096;
    } else {
      e = (i - nx8 - 2 * nw8) << 3;  src = w2; dst = w2b; sarr = w2s; K = 14336;
    }
    const int KB = K >> 7;
    const int n = (int)(e / K);
    const int k = (int)(e % K);
    const float sc = sarr[(n >> 7) * KB + (k >> 7)];
    f32x4 a = *(const f32x4*)(src + e);
    f32x4 b = *(const f32x4*)(src + e + 4);
    u16x8 q;
    #pragma unroll
    for (int j = 0; j < 4; ++j) { q[j] = f2bf(a[j] * sc); q[4 + j] = f2bf(b[j] * sc); }
    *(u16x8*)(dst + e) = q;
  }
}

// ---------------------------------------------------------------------------
// Fused gate+up GEMM + SwiGLU (R9-proven, byte-identical structure):
//   h = silu(xb @ w1b^T) * (xb @ w3b^T)  -> bf16 [M][N]
// BM=256, BN=128, BK=64; 512 thr = 8 waves (2Mx4N). MFMA 16x16x32.
// LDS 128KB: A dbuf 64KB (slots (2t+h)&3), B1 32KB + B3 32KB (slots t&1).
// vmcnt(8) top-of-loop, lgkm(0)+barrier before stage(t+2). Swizzle:
// pre-swizzled global src + XOR on ds_read (0 conflicts, R5/R9-proven).
// NOTE: 32x32x16 MFMA variant REGRESSED (R10): its 32-row x 2-slot read
// pattern defeats this swizzle (4.4e7 conflicts). Keep 16x16x32.
// ---------------------------------------------------------------------------
__global__ __launch_bounds__(512, 2)
void k_gateup_f(const unsigned short* __restrict__ A,
                const unsigned short* __restrict__ B1,
                const unsigned short* __restrict__ B3,
                unsigned short* __restrict__ H,
                int N, int K) {
  __shared__ unsigned short lds[65536];   // 128KB

  const int tid  = threadIdx.x;
  const int lane = tid & 63;
  const int wid  = tid >> 6;
  const int wm   = wid >> 2;              // 0..1
  const int wn   = wid & 3;               // 0..3
  const int lr   = lane & 15;
  const int kg   = lane >> 4;
  const int xr   = (lr & 7) << 4;

  const int nwg = gridDim.x;              // 896, %8==0
  const int per = nwg >> 3;
  const int wg  = (int)blockIdx.x;
  const int swz = (wg & 7) * per + (wg >> 3);
  const int bm  = swz & 7;                // M/256 = 8, fastest
  const int bn  = swz >> 3;               // 0..111

  const int r0   = tid >> 3;
  const int colb = ((tid & 7) ^ ((tid >> 3) & 7)) << 4;
  const size_t ldb = (size_t)K * 2;

  const char* gA = (const char*)A  + (size_t)bm * 256 * ldb;
  const char* g1 = (const char*)B1 + (size_t)bn * 128 * ldb;
  const char* g3 = (const char*)B3 + (size_t)bn * 128 * ldb;

  auto stage = [&](int t) {
    const size_t kb = (size_t)t * 128;
    #pragma unroll
    for (int h = 0; h < 2; ++h) {          // A: 4 loads
      unsigned short* d = lds + (((2 * t + h) & 3) * 8192) + wid * 512;
      const char* s = gA + (size_t)(h * 128 + r0) * ldb + kb + colb;
      gl_lds16(s,            d);
      gl_lds16(s + 64 * ldb, d + 4096);
    }
    {                                      // B1: 2 loads
      unsigned short* d = lds + 32768 + ((t & 1) * 8192) + wid * 512;
      const char* s = g1 + (size_t)r0 * ldb + kb + colb;
      gl_lds16(s,            d);
      gl_lds16(s + 64 * ldb, d + 4096);
    }
    {                                      // B3: 2 loads
      unsigned short* d = lds + 49152 + ((t & 1) * 8192) + wid * 512;
      const char* s = g3 + (size_t)r0 * ldb + kb + colb;
      gl_lds16(s,            d);
      gl_lds16(s + 64 * ldb, d + 4096);
    }
  };

  f32x4 accg[8][2], accu[8][2];
  #pragma unroll
  for (int m = 0; m < 8; ++m)
    #pragma unroll
    for (int n = 0; n < 2; ++n)
      #pragma unroll
      for (int e = 0; e < 4; ++e) { accg[m][n][e] = 0.0f; accu[m][n][e] = 0.0f; }

  const int wrow0 = wn * 32;
  const int NT = K >> 6;

  stage(0);
  stage(1);

  for (int t = 0; t < NT; ++t) {
    if (t == NT - 1) asm volatile("s_waitcnt vmcnt(0)" ::: "memory");
    else             asm volatile("s_waitcnt vmcnt(8)" ::: "memory");
    __builtin_amdgcn_s_barrier();
    __builtin_amdgcn_sched_barrier(0);

    const char* ab  = (const char*)lds + (((2 * t + wm) & 3) * 16384);
    const char* b1b = (const char*)lds + 65536 + ((t & 1) * 16384);
    const char* b3b = (const char*)lds + 98304 + ((t & 1) * 16384);

    short8 a0[8], p0[2], q0[2], a1[8], p1[2], q1[2];
    #pragma unroll
    for (int m = 0; m < 8; ++m)
      a0[m] = *(const short8*)(ab + ((((m * 16 + lr) * 128) + kg * 16) ^ xr));
    #pragma unroll
    for (int n = 0; n < 2; ++n) {
      p0[n] = *(const short8*)(b1b + ((((wrow0 + n * 16 + lr) * 128) + kg * 16) ^ xr));
      q0[n] = *(const short8*)(b3b + ((((wrow0 + n * 16 + lr) * 128) + kg * 16) ^ xr));
    }
    #pragma unroll
    for (int m = 0; m < 8; ++m)
      #pragma unroll
      for (int n = 0; n < 2; ++n) {
        accg[m][n] = mfma_bf16(a0[m], p0[n], accg[m][n]);
        accu[m][n] = mfma_bf16(a0[m], q0[n], accu[m][n]);
      }

    #pragma unroll
    for (int m = 0; m < 8; ++m)
      a1[m] = *(const short8*)(ab + ((((m * 16 + lr) * 128) + 64 + kg * 16) ^ xr));
    #pragma unroll
    for (int n = 0; n < 2; ++n) {
      p1[n] = *(const short8*)(b1b + ((((wrow0 + n * 16 + lr) * 128) + 64 + kg * 16) ^ xr));
      q1[n] = *(const short8*)(b3b + ((((wrow0 + n * 16 + lr) * 128) + 64 + kg * 16) ^ xr));
    }

    asm volatile("s_waitcnt lgkmcnt(0)" ::: "memory");
    __builtin_amdgcn_s_barrier();
    __builtin_amdgcn_sched_barrier(0);
    if (t + 2 < NT) stage(t + 2);
    __builtin_amdgcn_sched_barrier(0);

    #pragma unroll
    for (int m = 0; m < 8; ++m)
      #pragma unroll
      for (int n = 0; n < 2; ++n) {
        accg[m][n] = mfma_bf16(a1[m], p1[n], accg[m][n]);
        accu[m][n] = mfma_bf16(a1[m], q1[n], accu[m][n]);
      }
  }

  // epilogue: silu(g)*u -> bf16; C/D map col=lane&15, row=(lane>>4)*4+j
  const int growb = bm * 256 + wm * 128 + kg * 4;
  const int gcolb = bn * 128 + wn * 32 + lr;
  #pragma unroll
  for (int m = 0; m < 8; ++m)
    #pragma unroll
    for (int n = 0; n < 2; ++n)
      #pragma unroll
      for (int j = 0; j < 4; ++j) {
        const float g  = accg[m][n][j];
        const float u  = accu[m][n][j];
        const float sg = g / (1.0f + __expf(-g));
        H[(size_t)(growb + m * 16 + j) * N + (gcolb + n * 16)] = f2bf(sg * u);
      }
}

// ---------------------------------------------------------------------------
// Down GEMM (R9-proven): y = h @ w2b^T, f32 out. BM=256, BN=128.
// ---------------------------------------------------------------------------
__global__ __launch_bounds__(512, 2)
void k_down256(const unsigned short* __restrict__ A,
               const unsigned short* __restrict__ B,
               float* __restrict__ Y,
               int N, int K) {
  __shared__ unsigned short lds[65536];   // 128KB (A ring 64KB + B ring 64KB)

  const int tid  = threadIdx.x;
  const int lane = tid & 63;
  const int wid  = tid >> 6;
  const int wm   = wid >> 2;
  const int wn   = wid & 3;
  const int lr   = lane & 15;
  const int kg   = lane >> 4;
  const int xr   = (lr & 7) << 4;

  const int nwg = gridDim.x;              // 256
  const int per = nwg >> 3;
  const int wg  = (int)blockIdx.x;
  const int swz = (wg & 7) * per + (wg >> 3);
  const int bm  = swz & 7;
  const int bn  = swz >> 3;

  const int r0   = tid >> 3;
  const int colb = ((tid & 7) ^ ((tid >> 3) & 7)) << 4;
  const size_t ldb = (size_t)K * 2;

  const char* gA = (const char*)A + (size_t)bm * 256 * ldb;
  const char* gB = (const char*)B + (size_t)bn * 128 * ldb;

  auto stage = [&](int t) {
    const size_t kb = (size_t)t * 128;
    #pragma unroll
    for (int h = 0; h < 2; ++h) {
      unsigned short* d = lds + (((2 * t + h) & 3) * 8192) + wid * 512;
      const char* s = gA + (size_t)(h * 128 + r0) * ldb + kb + colb;
      gl_lds16(s,            d);
      gl_lds16(s + 64 * ldb, d + 4096);
    }
    {
      unsigned short* d = lds + 32768 + ((t & 3) * 8192) + wid * 512;
      const char* s = gB + (size_t)r0 * ldb + kb + colb;
      gl_lds16(s,            d);
      gl_lds16(s + 64 * ldb, d + 4096);
    }
  };

  f32x4 acc[8][2];
  #pragma unroll
  for (int m = 0; m < 8; ++m)
    #pragma unroll
    for (int n = 0; n < 2; ++n)
      #pragma unroll
      for (int e = 0; e < 4; ++e) acc[m][n][e] = 0.0f;

  const int wrow0 = wn * 32;
  const int NT = K >> 6;

  stage(0);
  stage(1);

  for (int t = 0; t < NT; ++t) {
    if (t == NT - 1) asm volatile("s_waitcnt vmcnt(0)" ::: "memory");
    else             asm volatile("s_waitcnt vmcnt(6)" ::: "memory");
    __builtin_amdgcn_s_barrier();
    __builtin_amdgcn_sched_barrier(0);

    const char* ab = (const char*)lds + (((2 * t + wm) & 3) * 16384);
    const char* bb = (const char*)lds + 65536 + ((t & 3) * 16384);

    short8 a0[8], b0[2], a1[8], b1[2];
    #pragma unroll
    for (int m = 0; m < 8; ++m)
      a0[m] = *(const short8*)(ab + ((((m * 16 + lr) * 128) + kg * 16) ^ xr));
    #pragma unroll
    for (int n = 0; n < 2; ++n)
      b0[n] = *(const short8*)(bb + ((((wrow0 + n * 16 + lr) * 128) + kg * 16) ^ xr));
    #pragma unroll
    for (int m = 0; m < 8; ++m)
      #pragma unroll
      for (int n = 0; n < 2; ++n)
        acc[m][n] = mfma_bf16(a0[m], b0[n], acc[m][n]);

    #pragma unroll
    for (int m = 0; m < 8; ++m)
      a1[m] = *(const short8*)(ab + ((((m * 16 + lr) * 128) + 64 + kg * 16) ^ xr));
    #pragma unroll
    for (int n = 0; n < 2; ++n)
      b1[n] = *(const short8*)(bb + ((((wrow0 + n * 16 + lr) * 128) + 64 + kg * 16) ^ xr));

    asm volatile("s_waitcnt lgkmcnt(0)" ::: "memory");
    __builtin_amdgcn_s_barrier();
    __builtin_amdgcn_sched_barrier(0);
    if (t + 2 < NT) stage(t + 2);
    __builtin_amdgcn_sched_barrier(0);

    #pragma unroll
    for (int m = 0; m < 8; ++m)
      #pragma unroll
      for (int n = 0; n < 2; ++n)
        acc[m][n] = mfma_bf16(a1[m], b1[n], acc[m][n]);
  }

  const int growb = bm * 256 + wm * 128 + kg * 4;
  const int gcolb = bn * 128 + wn * 32 + lr;
  #pragma unroll
  for (int m = 0; m < 8; ++m)
    #pragma unroll
    for (int n = 0; n < 2; ++n)
      #pragma unroll
      for (int j = 0; j < 4; ++j)
        Y[(size_t)(growb + m * 16 + j) * N + (gcolb + n * 16)] = acc[m][n][j];
}

extern "C" void kernel_launch(void* const* d_in, const int* in_sizes, int n_in,
                              void* d_out, int out_size, void* d_ws, size_t ws_size,
                              hipStream_t stream) {
  const float* x   = (const float*)d_in[0];
  const float* w1  = (const float*)d_in[1];
  const float* w1s = (const float*)d_in[2];
  const float* w3  = (const float*)d_in[3];
  const float* w3s = (const float*)d_in[4];
  const float* w2  = (const float*)d_in[5];
  const float* w2s = (const float*)d_in[6];
  float* y = (float*)d_out;

  const int D = 4096, I = 14336;
  const int T = in_sizes[0] / D;          // 2048

  const size_t xbB = (size_t)T * D * 2;
  const size_t wB  = (size_t)I * D * 2;

  char* ws = (char*)d_ws;
  unsigned short* xb  = (unsigned short*)(ws);
  unsigned short* w1b = (unsigned short*)(ws + xbB);
  unsigned short* w3b = (unsigned short*)(ws + xbB + wB);
  unsigned short* w2b = (unsigned short*)(ws + xbB + 2 * wB);
  unsigned short* h   = (unsigned short*)(ws + xbB + 3 * wB);

  // single merged convert pass (x, w1, w3, w2) — HBM-roofline-bound
  k_cvt_all<<<4096, 256, 0, stream>>>(
      x, w1, w1s, w3, w3s, w2, w2s, xb, w1b, w3b, w2b,
      ((size_t)T * D) >> 3, ((size_t)I * D) >> 3, ((size_t)D * I) >> 3);

  // fused gate+up+SwiGLU: h = silu(xb@w1b^T) * (xb@w3b^T)   grid 8*112 = 896
  k_gateup_f<<<dim3((T / 256) * (I / 128)), dim3(512), 0, stream>>>(
      xb, w1b, w3b, h, I, D);
  // down: y = h @ w2b^T                                     grid 8*32 = 256
  k_down256<<<dim3((T / 256) * (D / 128)), dim3(512), 0, stream>>>(
      h, w2b, y, D, I);
}